// Round 5
// baseline (1037.549 us; speedup 1.0000x reference)
//
#include <hip/hip_runtime.h>
#include <hip/hip_bf16.h>
#include <hip/hip_cooperative_groups.h>
#include <math.h>

// EncoderLayer_68186900791439 — graph transformer encoder layer on MI355X.
// Round 5: 4 dispatches.
//  1) cooperative build_kernel: prep weights + LN1 + zero + hist + scan + scatter
//  2) mfma QKV+skip GEMM (M=896)
//  3) attn: 2-edges-per-wave slot layout, online softmax, fused mean+skip+resid+LN2
//  4) fused FFN: GELU GEMM -> LDS -> GEMM + residual

typedef unsigned short u16;
using short8 = __attribute__((ext_vector_type(8))) short;
using f32x4  = __attribute__((ext_vector_type(4))) float;

__device__ __forceinline__ float bf2f(u16 u) {
    return __uint_as_float(((unsigned int)u) << 16);
}
__device__ __forceinline__ u16 f2bf(float f) {
    __hip_bfloat16 h = __float2bfloat16(f);
    return __builtin_bit_cast(u16, h);
}
__device__ __forceinline__ float bfe(short8 v, int j) {
    return bf2f((u16)v[j]);
}

// =================== cooperative build kernel =====================
struct BuildArgs {
    const float *x, *ln1g, *ln1b;
    const float *Wq, *Wk, *Wv, *Ws, *W1, *W2;
    const float *bq, *bk, *bv, *bs;
    u16 *wt; float *bc;          // transposed bf16 weights, concat bias
    u16 *y;                      // LN1 out
    const int *src, *dst;
    int *cnt, *cursor, *rowptr, *esrc, *bsum, *bsumex;
    int n, e, nchunks;
};

__global__ __launch_bounds__(256, 4) void build_kernel(BuildArgs a) {
    cooperative_groups::grid_group grid = cooperative_groups::this_grid();
    __shared__ int s[256];
    int tid = threadIdx.x, bid = blockIdx.x;
    int gsz = gridDim.x * 256;
    int gtid = bid * 256 + tid;

    // ---- P0a: weight transpose+convert + bias concat ----
    for (int i = gtid; i < 147456 + 896; i += gsz) {
        if (i < 147456) {
            const float* W; int N; int base;
            if      (i <  32768) { W = a.Wq; N = 256; base = 0; }
            else if (i <  65536) { W = a.Wk; N = 256; base = 32768; }
            else if (i <  98304) { W = a.Wv; N = 256; base = 65536; }
            else if (i < 114688) { W = a.Ws; N = 128; base = 98304; }
            else if (i < 131072) { W = a.W1; N = 128; base = 114688; }
            else                 { W = a.W2; N = 128; base = 131072; }
            int j = i - base;
            int nIdx = j >> 7, k = j & 127;
            a.wt[i] = f2bf(W[(size_t)k * N + nIdx]);
        } else {
            int j = i - 147456;
            float v;
            if      (j < 256) v = a.bq[j];
            else if (j < 512) v = a.bk[j - 256];
            else if (j < 768) v = a.bv[j - 512];
            else              v = a.bs[j - 768];
            a.bc[j] = v;
        }
    }
    // ---- P0b: zero histogram ----
    for (int i = gtid; i < a.n; i += gsz) a.cnt[i] = 0;
    // ---- P0c: LN1 (wave per row) ----
    {
        int lane = tid & 63;
        int gw = gtid >> 6, nw = gsz >> 6;
        for (int row = gw; row < a.n; row += nw) {
            size_t base = (size_t)row * 128;
            float v0 = a.x[base + lane];
            float v1 = a.x[base + 64 + lane];
            float s1 = v0 + v1, s2 = v0 * v0 + v1 * v1;
            for (int o = 1; o <= 32; o <<= 1) {
                s1 += __shfl_xor(s1, o);
                s2 += __shfl_xor(s2, o);
            }
            float mu = s1 * (1.f / 128.f);
            float var = s2 * (1.f / 128.f) - mu * mu;
            float rstd = rsqrtf(var + 1e-5f);
            a.y[base + lane]      = f2bf((v0 - mu) * rstd * a.ln1g[lane] + a.ln1b[lane]);
            a.y[base + 64 + lane] = f2bf((v1 - mu) * rstd * a.ln1g[64 + lane] + a.ln1b[64 + lane]);
        }
    }
    grid.sync();
    // ---- P1: histogram ----
    for (int i = gtid; i < a.e; i += gsz) atomicAdd(&a.cnt[a.dst[i]], 1);
    grid.sync();
    // ---- P2: per-chunk sums ----
    if (bid < a.nchunks) {
        int idx = bid * 256 + tid;
        s[tid] = (idx < a.n) ? a.cnt[idx] : 0;
        __syncthreads();
        for (int o = 128; o > 0; o >>= 1) {
            if (tid < o) s[tid] += s[tid + o];
            __syncthreads();
        }
        if (tid == 0) a.bsum[bid] = s[0];
    }
    grid.sync();
    // ---- P3: scan chunk sums (block 0) ----
    if (bid == 0) {
        int v = (tid < a.nchunks) ? a.bsum[tid] : 0;
        s[tid] = v;
        __syncthreads();
        for (int o = 1; o < 256; o <<= 1) {
            int add = (tid >= o) ? s[tid - o] : 0;
            __syncthreads();
            s[tid] += add;
            __syncthreads();
        }
        a.bsumex[tid] = s[tid] - v;
    }
    grid.sync();
    // ---- P4: per-chunk exclusive scan -> rowptr/cursor ----
    if (bid < a.nchunks) {
        int idx = bid * 256 + tid;
        int v = (idx < a.n) ? a.cnt[idx] : 0;
        s[tid] = v;
        __syncthreads();
        for (int o = 1; o < 256; o <<= 1) {
            int add = (tid >= o) ? s[tid - o] : 0;
            __syncthreads();
            s[tid] += add;
            __syncthreads();
        }
        if (idx < a.n) {
            int ex = a.bsumex[bid] + s[tid] - v;
            a.rowptr[idx] = ex;
            a.cursor[idx] = ex;
        }
    }
    if (gtid == 0) a.rowptr[a.n] = a.e;
    grid.sync();
    // ---- P5: scatter src ids grouped by dst ----
    for (int i = gtid; i < a.e; i += gsz) {
        int p = atomicAdd(&a.cursor[a.dst[i]], 1);
        a.esrc[p] = a.src[i];
    }
}

// =============== MFMA GEMM: qkv+skip, C = A@Bt^T + bias ===============
// A[n x 128] bf16, Bt [896 x 128] bf16. Block 64 rows x 128 cols (2x2 waves,
// wave 32x64). cols<768 -> bf16 qkv[row*768+col]; cols>=768 -> f32 skip.
__global__ __launch_bounds__(256) void qkv_gemm(
    const u16* __restrict__ A, const u16* __restrict__ Bt,
    const float* __restrict__ bias, u16* __restrict__ qkv,
    float* __restrict__ skip, int n)
{
    int wid = threadIdx.x >> 6, lane = threadIdx.x & 63;
    int wr = wid >> 1, wc = wid & 1;
    int r0 = blockIdx.x * 64 + wr * 32;
    int c0 = blockIdx.y * 128 + wc * 64;
    int lm = lane & 15, quad = lane >> 4;

    const u16* aBase = A  + (size_t)(r0 + lm) * 128 + quad * 8;
    const u16* bBase = Bt + (size_t)(c0 + lm) * 128 + quad * 8;

    f32x4 acc[2][4] = {};
#pragma unroll
    for (int kk = 0; kk < 128; kk += 32) {
        short8 a0 = *(const short8*)(aBase + kk);
        short8 a1 = *(const short8*)(aBase + 16 * 128 + kk);
#pragma unroll
        for (int j = 0; j < 4; ++j) {
            short8 bj = *(const short8*)(bBase + (size_t)j * 16 * 128 + kk);
            acc[0][j] = __builtin_amdgcn_mfma_f32_16x16x32_bf16(a0, bj, acc[0][j], 0, 0, 0);
            acc[1][j] = __builtin_amdgcn_mfma_f32_16x16x32_bf16(a1, bj, acc[1][j], 0, 0, 0);
        }
    }
#pragma unroll
    for (int j = 0; j < 4; ++j) {
        int col = c0 + j * 16 + lm;
        float bv = bias[col];
#pragma unroll
        for (int rt = 0; rt < 2; ++rt) {
#pragma unroll
            for (int i2 = 0; i2 < 4; ++i2) {
                int row = r0 + rt * 16 + quad * 4 + i2;
                if (row >= n) continue;
                float v = acc[rt][j][i2] + bv;
                if (col < 768)
                    qkv[(size_t)row * 768 + col] = f2bf(v);
                else
                    skip[(size_t)row * 128 + col - 768] = v;
            }
        }
    }
}

// =============== Attention: wave per dst, 2 edge slots =================
// Lane layout: slot=lane>>5 (edge slot), head=(lane>>4)&1, sub=lane&15.
// Lane owns 8 cols: head*128 + sub*8. Each 32-lane slot runs an independent
// online softmax over its half of the edges; merged at the end. Epilogue:
// slot-merge + head-mean + skip + residual (sx in place) + LayerNorm2 -> y.
__global__ __launch_bounds__(256) void attn_kernel(
    const u16* __restrict__ qkv, const int* __restrict__ rowptr,
    const int* __restrict__ esrc, const float* __restrict__ x,
    float* __restrict__ sx, const float* __restrict__ g2,
    const float* __restrict__ b2, u16* __restrict__ y, int n)
{
    int wid = threadIdx.x >> 6, lane = threadIdx.x & 63;
    int i = blockIdx.x * 4 + wid;
    if (i >= n) return;
    int slot = lane >> 5;
    int sub  = lane & 15;
    int colOff = ((lane >> 4) & 1) * 128 + sub * 8;

    short8 q8 = *(const short8*)(qkv + (size_t)i * 768 + colOff);
    float qf[8];
#pragma unroll
    for (int j = 0; j < 8; ++j) qf[j] = bfe(q8, j);

    int beg = rowptr[i], end = rowptr[i + 1];
    float m = -INFINITY, l = 0.f;
    float acc[8] = {};
    const float scale = 0.08838834764831845f;   // 1/sqrt(128)

    int t = beg + slot;
    for (; t + 2 < end; t += 4) {               // 2 edges per slot in flight
        int s0 = esrc[t], s1 = esrc[t + 2];
        const u16* b0 = qkv + (size_t)s0 * 768 + colOff;
        const u16* b1 = qkv + (size_t)s1 * 768 + colOff;
        short8 k0 = *(const short8*)(b0 + 256);
        short8 k1 = *(const short8*)(b1 + 256);
        short8 v0 = *(const short8*)(b0 + 512);
        short8 v1 = *(const short8*)(b1 + 512);
        float d0 = 0.f, d1 = 0.f;
#pragma unroll
        for (int j = 0; j < 8; ++j) {
            d0 += qf[j] * bfe(k0, j);
            d1 += qf[j] * bfe(k1, j);
        }
#pragma unroll
        for (int o = 1; o <= 8; o <<= 1) {      // reduce over 16-lane group
            d0 += __shfl_xor(d0, o);
            d1 += __shfl_xor(d1, o);
        }
        float al0 = d0 * scale, al1 = d1 * scale;
        float nm = fmaxf(m, fmaxf(al0, al1));
        float sc = expf(m - nm);                 // m=-inf first iter -> 0
        float w0 = expf(al0 - nm), w1 = expf(al1 - nm);
        l = l * sc + w0 + w1;
#pragma unroll
        for (int j = 0; j < 8; ++j)
            acc[j] = acc[j] * sc + w0 * bfe(v0, j) + w1 * bfe(v1, j);
        m = nm;
    }
    if (t < end) {                               // slot tail: single edge
        int s0 = esrc[t];
        const u16* b0 = qkv + (size_t)s0 * 768 + colOff;
        short8 k0 = *(const short8*)(b0 + 256);
        short8 v0 = *(const short8*)(b0 + 512);
        float d0 = 0.f;
#pragma unroll
        for (int j = 0; j < 8; ++j) d0 += qf[j] * bfe(k0, j);
#pragma unroll
        for (int o = 1; o <= 8; o <<= 1) d0 += __shfl_xor(d0, o);
        float al0 = d0 * scale;
        float nm = fmaxf(m, al0);
        float sc = expf(m - nm);
        float w0 = expf(al0 - nm);
        l = l * sc + w0;
#pragma unroll
        for (int j = 0; j < 8; ++j) acc[j] = acc[j] * sc + w0 * bfe(v0, j);
        m = nm;
    }

    // merge the two slots (guard exp(-inf - -inf) for degree<2 nodes)
    float mo = __shfl_xor(m, 32);
    float lo = __shfl_xor(l, 32);
    float nm = fmaxf(m, mo);
    float scS = (m  > -INFINITY) ? expf(m - nm)  : 0.f;
    float scO = (mo > -INFINITY) ? expf(mo - nm) : 0.f;
    l = l * scS + lo * scO;
    float inv = (l > 0.f) ? (1.f / l) : 0.f;
#pragma unroll
    for (int j = 0; j < 8; ++j) {
        float other = __shfl_xor(acc[j], 32);
        acc[j] = (acc[j] * scS + other * scO) * inv;
        acc[j] = 0.5f * (acc[j] + __shfl_xor(acc[j], 16));  // head mean
    }

    if (lane < 16) {                             // lanes 0..15 hold the row
        size_t base = (size_t)i * 128 + sub * 8;
        float4 xv0 = *(const float4*)(x + base);
        float4 xv1 = *(const float4*)(x + base + 4);
        float4 sk0 = *(const float4*)(sx + base);
        float4 sk1 = *(const float4*)(sx + base + 4);
        float r[8];
        r[0] = xv0.x + sk0.x + acc[0]; r[1] = xv0.y + sk0.y + acc[1];
        r[2] = xv0.z + sk0.z + acc[2]; r[3] = xv0.w + sk0.w + acc[3];
        r[4] = xv1.x + sk1.x + acc[4]; r[5] = xv1.y + sk1.y + acc[5];
        r[6] = xv1.z + sk1.z + acc[6]; r[7] = xv1.w + sk1.w + acc[7];
        *(float4*)(sx + base)     = make_float4(r[0], r[1], r[2], r[3]);
        *(float4*)(sx + base + 4) = make_float4(r[4], r[5], r[6], r[7]);
        // fused LayerNorm2 (reduce over the 16-lane row group)
        float s1 = 0.f, s2 = 0.f;
#pragma unroll
        for (int j = 0; j < 8; ++j) { s1 += r[j]; s2 += r[j] * r[j]; }
#pragma unroll
        for (int o = 1; o <= 8; o <<= 1) {
            s1 += __shfl_xor(s1, o);
            s2 += __shfl_xor(s2, o);
        }
        float mu = s1 * (1.f / 128.f);
        float var = s2 * (1.f / 128.f) - mu * mu;
        float rstd = rsqrtf(var + 1e-5f);
        short8 o8;
#pragma unroll
        for (int j = 0; j < 8; ++j)
            o8[j] = (short)f2bf((r[j] - mu) * rstd * g2[sub * 8 + j] + b2[sub * 8 + j]);
        *(short8*)(y + base) = o8;
    }
}

// =============== Fused FFN: out = x2 + gelu(y2@W1T+b1)@W2T+b2 ===============
// Block 64 rows; wave w computes 16 rows x 128 cols. T1 staged in LDS (pad +8).
__global__ __launch_bounds__(256) void ffn_kernel(
    const u16* __restrict__ y2, const u16* __restrict__ W1T,
    const float* __restrict__ b1, const u16* __restrict__ W2T,
    const float* __restrict__ b2, const float* __restrict__ x2,
    float* __restrict__ out, int n)
{
    __shared__ u16 t1[64 * 136];                 // 17 KB, padded leading dim
    int wid = threadIdx.x >> 6, lane = threadIdx.x & 63;
    int lm = lane & 15, quad = lane >> 4;
    int r0 = blockIdx.x * 64 + wid * 16;

    const u16* aBase = y2 + (size_t)(r0 + lm) * 128 + quad * 8;
    f32x4 acc[8] = {};
#pragma unroll
    for (int kk = 0; kk < 128; kk += 32) {
        short8 a0 = *(const short8*)(aBase + kk);
#pragma unroll
        for (int j = 0; j < 8; ++j) {
            short8 bj = *(const short8*)(W1T + (size_t)(j * 16 + lm) * 128 + quad * 8 + kk);
            acc[j] = __builtin_amdgcn_mfma_f32_16x16x32_bf16(a0, bj, acc[j], 0, 0, 0);
        }
    }
#pragma unroll
    for (int j = 0; j < 8; ++j) {
        int col = j * 16 + lm;
        float bv = b1[col];
#pragma unroll
        for (int i2 = 0; i2 < 4; ++i2) {
            int rl = wid * 16 + quad * 4 + i2;
            float v = acc[j][i2] + bv;
            v = 0.5f * v * (1.f + erff(v * 0.70710678118654752f));
            t1[rl * 136 + col] = f2bf(v);
        }
    }
    __syncthreads();

    f32x4 acc2[8] = {};
#pragma unroll
    for (int kk = 0; kk < 128; kk += 32) {
        short8 a0 = *(const short8*)(t1 + (wid * 16 + lm) * 136 + quad * 8 + kk);
#pragma unroll
        for (int j = 0; j < 8; ++j) {
            short8 bj = *(const short8*)(W2T + (size_t)(j * 16 + lm) * 128 + quad * 8 + kk);
            acc2[j] = __builtin_amdgcn_mfma_f32_16x16x32_bf16(a0, bj, acc2[j], 0, 0, 0);
        }
    }
#pragma unroll
    for (int j = 0; j < 8; ++j) {
        int col = j * 16 + lm;
        float bv = b2[col];
#pragma unroll
        for (int i2 = 0; i2 < 4; ++i2) {
            int row = r0 + quad * 4 + i2;
            if (row >= n) continue;
            size_t ob = (size_t)row * 128 + col;
            out[ob] = acc2[j][i2] + bv + x2[ob];
        }
    }
}

extern "C" void kernel_launch(void* const* d_in, const int* in_sizes, int n_in,
                              void* d_out, int out_size, void* d_ws, size_t ws_size,
                              hipStream_t stream)
{
    const float* x    = (const float*)d_in[0];
    const int*   ei   = (const int*)d_in[1];

    int n = in_sizes[0] / 128;     // 50000
    int e = in_sizes[1] / 2;       // 800000

    char* w = (char*)d_ws;
    size_t off = 0;
    auto alloc = [&](size_t bytes) -> void* {
        void* p = w + off;
        off = (off + bytes + 255) & ~(size_t)255;
        return p;
    };
    u16*   y    = (u16*)alloc((size_t)n * 128 * 2);   // LN1 out, then LN2 out
    u16*   qkv  = (u16*)alloc((size_t)n * 768 * 2);   // q|k|v interleaved
    float* sx   = (float*)alloc((size_t)n * 128 * 4); // skip, then x2 in-place
    u16*   wt   = (u16*)alloc((size_t)147456 * 2);
    float* bc   = (float*)alloc(896 * 4);
    int* cnt    = (int*)alloc((size_t)n * 4);
    int* cursor = (int*)alloc((size_t)n * 4);
    int* rowptr = (int*)alloc(((size_t)n + 1) * 4);
    int* esrc   = (int*)alloc((size_t)e * 4);
    int* bsum   = (int*)alloc(1024);
    int* bsumex = (int*)alloc(1024);

    BuildArgs args;
    args.x = x; args.ln1g = (const float*)d_in[2]; args.ln1b = (const float*)d_in[3];
    args.Wq = (const float*)d_in[4];  args.bq = (const float*)d_in[5];
    args.Wk = (const float*)d_in[6];  args.bk = (const float*)d_in[7];
    args.Wv = (const float*)d_in[8];  args.bv = (const float*)d_in[9];
    args.Ws = (const float*)d_in[10]; args.bs = (const float*)d_in[11];
    args.W1 = (const float*)d_in[14];
    args.W2 = (const float*)d_in[16];
    args.wt = wt; args.bc = bc; args.y = y;
    args.src = ei; args.dst = ei + e;
    args.cnt = cnt; args.cursor = cursor; args.rowptr = rowptr;
    args.esrc = esrc; args.bsum = bsum; args.bsumex = bsumex;
    args.n = n; args.e = e; args.nchunks = (n + 255) / 256;

    void* kparams[] = { (void*)&args };
    hipLaunchCooperativeKernel((const void*)build_kernel, dim3(1024), dim3(256),
                               kparams, 0, stream);

    int gr = (n + 63) / 64;
    qkv_gemm<<<dim3(gr, 7), 256, 0, stream>>>(y, wt, bc, qkv, sx, n);
    attn_kernel<<<(n + 3) / 4, 256, 0, stream>>>(qkv, rowptr, esrc, x, sx,
                                                 (const float*)d_in[12],
                                                 (const float*)d_in[13], y, n);
    ffn_kernel<<<gr, 256, 0, stream>>>(y, wt + 114688, (const float*)d_in[15],
                                       wt + 131072, (const float*)d_in[17],
                                       sx, (float*)d_out, n);
}

// Round 6
// 568.551 us; speedup vs baseline: 1.8249x; 1.8249x over previous
//
#include <hip/hip_runtime.h>
#include <hip/hip_bf16.h>
#include <math.h>

// EncoderLayer_68186900791439 — graph transformer encoder layer on MI355X.
// Round 6: plain launches only (round-5 lesson: grid.sync() ~100+ us each on
// gfx950 — coop kernel spent 650 us at VALUBusy 0.6% spinning). 7 dispatches:
//  1) fused_prep_ln: weight transpose/convert + bias concat + LN1 + zero cnt
//  2) hist  3) scan (single block)  4) scatter
//  5) qkv_gemm (M=896 fused q|k|v|skip)
//  6) attn: 2-edge-slot online softmax + mean + skip + residual + LN2
//  7) fused FFN: GELU GEMM -> LDS -> GEMM + residual

typedef unsigned short u16;
using short8 = __attribute__((ext_vector_type(8))) short;
using f32x4  = __attribute__((ext_vector_type(4))) float;

__device__ __forceinline__ float bf2f(u16 u) {
    return __uint_as_float(((unsigned int)u) << 16);
}
__device__ __forceinline__ u16 f2bf(float f) {
    __hip_bfloat16 h = __float2bfloat16(f);
    return __builtin_bit_cast(u16, h);
}
__device__ __forceinline__ float bfe(short8 v, int j) {
    return bf2f((u16)v[j]);
}

// ============ Kernel A: prep weights + bias concat + LN1 + zero cnt ==========
// All three jobs are independent; grid-stride over each. No internal ordering.
__global__ __launch_bounds__(256) void fused_prep_ln(
    const float* __restrict__ x, const float* __restrict__ ln1g,
    const float* __restrict__ ln1b,
    const float* __restrict__ Wq, const float* __restrict__ Wk,
    const float* __restrict__ Wv, const float* __restrict__ Ws,
    const float* __restrict__ W1, const float* __restrict__ W2,
    const float* __restrict__ bq, const float* __restrict__ bk,
    const float* __restrict__ bv, const float* __restrict__ bs,
    u16* __restrict__ wt, float* __restrict__ bc,
    u16* __restrict__ y, int* __restrict__ cnt, int n)
{
    int gsz = gridDim.x * 256;
    int gtid = blockIdx.x * 256 + threadIdx.x;

    // weights: W[128 x N] f32 -> Wt[N x 128] bf16 (q|k|v|skip|W1|W2) + bias
    for (int i = gtid; i < 147456 + 896; i += gsz) {
        if (i < 147456) {
            const float* W; int N; int base;
            if      (i <  32768) { W = Wq; N = 256; base = 0; }
            else if (i <  65536) { W = Wk; N = 256; base = 32768; }
            else if (i <  98304) { W = Wv; N = 256; base = 65536; }
            else if (i < 114688) { W = Ws; N = 128; base = 98304; }
            else if (i < 131072) { W = W1; N = 128; base = 114688; }
            else                 { W = W2; N = 128; base = 131072; }
            int j = i - base;
            int nIdx = j >> 7, k = j & 127;
            wt[i] = f2bf(W[(size_t)k * N + nIdx]);
        } else {
            int j = i - 147456;
            float v;
            if      (j < 256) v = bq[j];
            else if (j < 512) v = bk[j - 256];
            else if (j < 768) v = bv[j - 512];
            else              v = bs[j - 768];
            bc[j] = v;
        }
    }
    // zero histogram
    for (int i = gtid; i < n; i += gsz) cnt[i] = 0;
    // LN1: wave per row
    int lane = threadIdx.x & 63;
    int gw = gtid >> 6, nw = gsz >> 6;
    for (int row = gw; row < n; row += nw) {
        size_t base = (size_t)row * 128;
        float v0 = x[base + lane];
        float v1 = x[base + 64 + lane];
        float s1 = v0 + v1, s2 = v0 * v0 + v1 * v1;
        for (int o = 1; o <= 32; o <<= 1) {
            s1 += __shfl_xor(s1, o);
            s2 += __shfl_xor(s2, o);
        }
        float mu = s1 * (1.f / 128.f);
        float var = s2 * (1.f / 128.f) - mu * mu;
        float rstd = rsqrtf(var + 1e-5f);
        y[base + lane]      = f2bf((v0 - mu) * rstd * ln1g[lane] + ln1b[lane]);
        y[base + 64 + lane] = f2bf((v1 - mu) * rstd * ln1g[64 + lane] + ln1b[64 + lane]);
    }
}

// ============================ CSR build ====================================
__global__ __launch_bounds__(256) void hist_kernel(const int* __restrict__ dst,
                                                   int* __restrict__ cnt, int e) {
    int stride = gridDim.x * 256;
    for (int i = blockIdx.x * 256 + threadIdx.x; i < e; i += stride)
        atomicAdd(&cnt[dst[i]], 1);
}

// Single-block exclusive scan of cnt[0..n) -> rowptr/cursor. 1024 threads,
// per-thread serial chunk + one block scan (replaces 3-kernel chain).
__global__ __launch_bounds__(1024) void scan_kernel(
    const int* __restrict__ cnt, int* __restrict__ rowptr,
    int* __restrict__ cursor, int n, int e)
{
    __shared__ int sh[1024];
    int tid = threadIdx.x;
    int chunk = (n + 1023) / 1024;
    int lo = tid * chunk, hi = min(lo + chunk, n);
    int s = 0;
    for (int i = lo; i < hi; ++i) s += cnt[i];
    sh[tid] = s;
    __syncthreads();
    for (int o = 1; o < 1024; o <<= 1) {
        int add = (tid >= o) ? sh[tid - o] : 0;
        __syncthreads();
        sh[tid] += add;
        __syncthreads();
    }
    int run = sh[tid] - s;
    for (int i = lo; i < hi; ++i) {
        rowptr[i] = run;
        cursor[i] = run;
        run += cnt[i];
    }
    if (tid == 0) rowptr[n] = e;
}

// stores SRC NODE IDS grouped by dst — avoids eids indirection in attn
__global__ __launch_bounds__(256) void scatter_kernel(const int* __restrict__ dst,
                                                      const int* __restrict__ src,
                                                      int* __restrict__ cursor,
                                                      int* __restrict__ esrc, int e) {
    int stride = gridDim.x * 256;
    for (int i = blockIdx.x * 256 + threadIdx.x; i < e; i += stride) {
        int p = atomicAdd(&cursor[dst[i]], 1);
        esrc[p] = src[i];
    }
}

// =============== MFMA GEMM: qkv+skip, C = A@Bt^T + bias ===============
// A[n x 128] bf16, Bt [896 x 128] bf16. Block 64 rows x 128 cols (2x2 waves,
// wave 32x64). cols<768 -> bf16 qkv[row*768+col]; cols>=768 -> f32 skip.
__global__ __launch_bounds__(256) void qkv_gemm(
    const u16* __restrict__ A, const u16* __restrict__ Bt,
    const float* __restrict__ bias, u16* __restrict__ qkv,
    float* __restrict__ skip, int n)
{
    int wid = threadIdx.x >> 6, lane = threadIdx.x & 63;
    int wr = wid >> 1, wc = wid & 1;
    int r0 = blockIdx.x * 64 + wr * 32;
    int c0 = blockIdx.y * 128 + wc * 64;
    int lm = lane & 15, quad = lane >> 4;

    // Last row-block reads overrun n into the adjacent ws buffer — harmless,
    // those rows are never stored (row<n guard).
    const u16* aBase = A  + (size_t)(r0 + lm) * 128 + quad * 8;
    const u16* bBase = Bt + (size_t)(c0 + lm) * 128 + quad * 8;

    f32x4 acc[2][4] = {};
#pragma unroll
    for (int kk = 0; kk < 128; kk += 32) {
        short8 a0 = *(const short8*)(aBase + kk);
        short8 a1 = *(const short8*)(aBase + 16 * 128 + kk);
#pragma unroll
        for (int j = 0; j < 4; ++j) {
            short8 bj = *(const short8*)(bBase + (size_t)j * 16 * 128 + kk);
            acc[0][j] = __builtin_amdgcn_mfma_f32_16x16x32_bf16(a0, bj, acc[0][j], 0, 0, 0);
            acc[1][j] = __builtin_amdgcn_mfma_f32_16x16x32_bf16(a1, bj, acc[1][j], 0, 0, 0);
        }
    }
#pragma unroll
    for (int j = 0; j < 4; ++j) {
        int col = c0 + j * 16 + lm;
        float bv = bias[col];
#pragma unroll
        for (int rt = 0; rt < 2; ++rt) {
#pragma unroll
            for (int i2 = 0; i2 < 4; ++i2) {
                int row = r0 + rt * 16 + quad * 4 + i2;
                if (row >= n) continue;
                float v = acc[rt][j][i2] + bv;
                if (col < 768)
                    qkv[(size_t)row * 768 + col] = f2bf(v);
                else
                    skip[(size_t)row * 128 + col - 768] = v;
            }
        }
    }
}

// =============== Attention: wave per dst, 2 edge slots =================
// Lane layout: slot=lane>>5, head=(lane>>4)&1, sub=lane&15. Lane owns 8 cols.
// Each 32-lane slot runs an independent online softmax over alternating edges,
// merged at the end. Epilogue: merge + head-mean + skip + residual + LN2.
__global__ __launch_bounds__(256) void attn_kernel(
    const u16* __restrict__ qkv, const int* __restrict__ rowptr,
    const int* __restrict__ esrc, const float* __restrict__ x,
    float* __restrict__ sx, const float* __restrict__ g2,
    const float* __restrict__ b2, u16* __restrict__ y, int n)
{
    int wid = threadIdx.x >> 6, lane = threadIdx.x & 63;
    int i = blockIdx.x * 4 + wid;
    if (i >= n) return;
    int slot = lane >> 5;
    int sub  = lane & 15;
    int colOff = ((lane >> 4) & 1) * 128 + sub * 8;

    short8 q8 = *(const short8*)(qkv + (size_t)i * 768 + colOff);
    float qf[8];
#pragma unroll
    for (int j = 0; j < 8; ++j) qf[j] = bfe(q8, j);

    int beg = rowptr[i], end = rowptr[i + 1];
    float m = -INFINITY, l = 0.f;
    float acc[8] = {};
    const float scale = 0.08838834764831845f;   // 1/sqrt(128)

    int t = beg + slot;
    for (; t + 2 < end; t += 4) {               // 2 edges per slot in flight
        int s0 = esrc[t], s1 = esrc[t + 2];
        const u16* b0 = qkv + (size_t)s0 * 768 + colOff;
        const u16* b1 = qkv + (size_t)s1 * 768 + colOff;
        short8 k0 = *(const short8*)(b0 + 256);
        short8 k1 = *(const short8*)(b1 + 256);
        short8 v0 = *(const short8*)(b0 + 512);
        short8 v1 = *(const short8*)(b1 + 512);
        float d0 = 0.f, d1 = 0.f;
#pragma unroll
        for (int j = 0; j < 8; ++j) {
            d0 += qf[j] * bfe(k0, j);
            d1 += qf[j] * bfe(k1, j);
        }
#pragma unroll
        for (int o = 1; o <= 8; o <<= 1) {      // reduce over 16-lane group
            d0 += __shfl_xor(d0, o);
            d1 += __shfl_xor(d1, o);
        }
        float al0 = d0 * scale, al1 = d1 * scale;
        float nm = fmaxf(m, fmaxf(al0, al1));
        float sc = expf(m - nm);                 // m=-inf first iter -> 0
        float w0 = expf(al0 - nm), w1 = expf(al1 - nm);
        l = l * sc + w0 + w1;
#pragma unroll
        for (int j = 0; j < 8; ++j)
            acc[j] = acc[j] * sc + w0 * bfe(v0, j) + w1 * bfe(v1, j);
        m = nm;
    }
    if (t < end) {                               // slot tail: single edge
        int s0 = esrc[t];
        const u16* b0 = qkv + (size_t)s0 * 768 + colOff;
        short8 k0 = *(const short8*)(b0 + 256);
        short8 v0 = *(const short8*)(b0 + 512);
        float d0 = 0.f;
#pragma unroll
        for (int j = 0; j < 8; ++j) d0 += qf[j] * bfe(k0, j);
#pragma unroll
        for (int o = 1; o <= 8; o <<= 1) d0 += __shfl_xor(d0, o);
        float al0 = d0 * scale;
        float nm = fmaxf(m, al0);
        float sc = expf(m - nm);
        float w0 = expf(al0 - nm);
        l = l * sc + w0;
#pragma unroll
        for (int j = 0; j < 8; ++j) acc[j] = acc[j] * sc + w0 * bfe(v0, j);
        m = nm;
    }

    // merge the two slots (guard exp(-inf - -inf) for degree<2 nodes)
    float mo = __shfl_xor(m, 32);
    float lo = __shfl_xor(l, 32);
    float nm = fmaxf(m, mo);
    float scS = (m  > -INFINITY) ? expf(m - nm)  : 0.f;
    float scO = (mo > -INFINITY) ? expf(mo - nm) : 0.f;
    l = l * scS + lo * scO;
    float inv = (l > 0.f) ? (1.f / l) : 0.f;
#pragma unroll
    for (int j = 0; j < 8; ++j) {
        float other = __shfl_xor(acc[j], 32);
        acc[j] = (acc[j] * scS + other * scO) * inv;
        acc[j] = 0.5f * (acc[j] + __shfl_xor(acc[j], 16));  // head mean
    }

    if (lane < 16) {                             // lanes 0..15 hold the row
        size_t base = (size_t)i * 128 + sub * 8;
        float4 xv0 = *(const float4*)(x + base);
        float4 xv1 = *(const float4*)(x + base + 4);
        float4 sk0 = *(const float4*)(sx + base);
        float4 sk1 = *(const float4*)(sx + base + 4);
        float r[8];
        r[0] = xv0.x + sk0.x + acc[0]; r[1] = xv0.y + sk0.y + acc[1];
        r[2] = xv0.z + sk0.z + acc[2]; r[3] = xv0.w + sk0.w + acc[3];
        r[4] = xv1.x + sk1.x + acc[4]; r[5] = xv1.y + sk1.y + acc[5];
        r[6] = xv1.z + sk1.z + acc[6]; r[7] = xv1.w + sk1.w + acc[7];
        *(float4*)(sx + base)     = make_float4(r[0], r[1], r[2], r[3]);
        *(float4*)(sx + base + 4) = make_float4(r[4], r[5], r[6], r[7]);
        // fused LayerNorm2 (reduce over the 16-lane row group)
        float s1 = 0.f, s2 = 0.f;
#pragma unroll
        for (int j = 0; j < 8; ++j) { s1 += r[j]; s2 += r[j] * r[j]; }
#pragma unroll
        for (int o = 1; o <= 8; o <<= 1) {
            s1 += __shfl_xor(s1, o);
            s2 += __shfl_xor(s2, o);
        }
        float mu = s1 * (1.f / 128.f);
        float var = s2 * (1.f / 128.f) - mu * mu;
        float rstd = rsqrtf(var + 1e-5f);
        short8 o8;
#pragma unroll
        for (int j = 0; j < 8; ++j)
            o8[j] = (short)f2bf((r[j] - mu) * rstd * g2[sub * 8 + j] + b2[sub * 8 + j]);
        *(short8*)(y + base) = o8;
    }
}

// =============== Fused FFN: out = x2 + gelu(y2@W1T+b1)@W2T+b2 ===============
// Block 64 rows; wave w computes 16 rows x 128 cols. T1 staged in LDS (pad +8).
__global__ __launch_bounds__(256) void ffn_kernel(
    const u16* __restrict__ y2, const u16* __restrict__ W1T,
    const float* __restrict__ b1, const u16* __restrict__ W2T,
    const float* __restrict__ b2, const float* __restrict__ x2,
    float* __restrict__ out, int n)
{
    __shared__ u16 t1[64 * 136];                 // 17 KB, padded leading dim
    int wid = threadIdx.x >> 6, lane = threadIdx.x & 63;
    int lm = lane & 15, quad = lane >> 4;
    int r0 = blockIdx.x * 64 + wid * 16;

    const u16* aBase = y2 + (size_t)(r0 + lm) * 128 + quad * 8;
    f32x4 acc[8] = {};
#pragma unroll
    for (int kk = 0; kk < 128; kk += 32) {
        short8 a0 = *(const short8*)(aBase + kk);
#pragma unroll
        for (int j = 0; j < 8; ++j) {
            short8 bj = *(const short8*)(W1T + (size_t)(j * 16 + lm) * 128 + quad * 8 + kk);
            acc[j] = __builtin_amdgcn_mfma_f32_16x16x32_bf16(a0, bj, acc[j], 0, 0, 0);
        }
    }
#pragma unroll
    for (int j = 0; j < 8; ++j) {
        int col = j * 16 + lm;
        float bv = b1[col];
#pragma unroll
        for (int i2 = 0; i2 < 4; ++i2) {
            int rl = wid * 16 + quad * 4 + i2;
            float v = acc[j][i2] + bv;
            v = 0.5f * v * (1.f + erff(v * 0.70710678118654752f));
            t1[rl * 136 + col] = f2bf(v);
        }
    }
    __syncthreads();

    f32x4 acc2[8] = {};
#pragma unroll
    for (int kk = 0; kk < 128; kk += 32) {
        short8 a0 = *(const short8*)(t1 + (wid * 16 + lm) * 136 + quad * 8 + kk);
#pragma unroll
        for (int j = 0; j < 8; ++j) {
            short8 bj = *(const short8*)(W2T + (size_t)(j * 16 + lm) * 128 + quad * 8 + kk);
            acc2[j] = __builtin_amdgcn_mfma_f32_16x16x32_bf16(a0, bj, acc2[j], 0, 0, 0);
        }
    }
#pragma unroll
    for (int j = 0; j < 8; ++j) {
        int col = j * 16 + lm;
        float bv = b2[col];
#pragma unroll
        for (int i2 = 0; i2 < 4; ++i2) {
            int row = r0 + quad * 4 + i2;
            if (row >= n) continue;
            size_t ob = (size_t)row * 128 + col;
            out[ob] = acc2[j][i2] + bv + x2[ob];
        }
    }
}

extern "C" void kernel_launch(void* const* d_in, const int* in_sizes, int n_in,
                              void* d_out, int out_size, void* d_ws, size_t ws_size,
                              hipStream_t stream)
{
    const float* x    = (const float*)d_in[0];
    const int*   ei   = (const int*)d_in[1];

    int n = in_sizes[0] / 128;     // 50000
    int e = in_sizes[1] / 2;       // 800000
    const int* src  = ei;          // edge_index[0] (messages src -> dst)
    const int* dstp = ei + e;      // edge_index[1]

    char* w = (char*)d_ws;
    size_t off = 0;
    auto alloc = [&](size_t bytes) -> void* {
        void* p = w + off;
        off = (off + bytes + 255) & ~(size_t)255;
        return p;
    };
    u16*   y    = (u16*)alloc((size_t)n * 128 * 2);   // LN1 out, then LN2 out
    u16*   qkv  = (u16*)alloc((size_t)n * 768 * 2);   // q|k|v interleaved
    float* sx   = (float*)alloc((size_t)n * 128 * 4); // skip, then x2 in-place
    u16*   wt   = (u16*)alloc((size_t)147456 * 2);
    float* bc   = (float*)alloc(896 * 4);
    int* cnt    = (int*)alloc((size_t)n * 4);
    int* cursor = (int*)alloc((size_t)n * 4);
    int* rowptr = (int*)alloc(((size_t)n + 1) * 4);
    int* esrc   = (int*)alloc((size_t)e * 4);

    int gr = (n + 63) / 64;

    fused_prep_ln<<<832, 256, 0, stream>>>(
        x, (const float*)d_in[2], (const float*)d_in[3],
        (const float*)d_in[4], (const float*)d_in[6], (const float*)d_in[8],
        (const float*)d_in[10], (const float*)d_in[14], (const float*)d_in[16],
        (const float*)d_in[5], (const float*)d_in[7], (const float*)d_in[9],
        (const float*)d_in[11], wt, bc, y, cnt, n);
    hist_kernel<<<1024, 256, 0, stream>>>(dstp, cnt, e);
    scan_kernel<<<1, 1024, 0, stream>>>(cnt, rowptr, cursor, n, e);
    scatter_kernel<<<1024, 256, 0, stream>>>(dstp, src, cursor, esrc, e);
    qkv_gemm<<<dim3(gr, 7), 256, 0, stream>>>(y, wt, bc, qkv, sx, n);
    attn_kernel<<<(n + 3) / 4, 256, 0, stream>>>(qkv, rowptr, esrc, x, sx,
                                                 (const float*)d_in[12],
                                                 (const float*)d_in[13], y, n);
    ffn_kernel<<<gr, 256, 0, stream>>>(y, wt + 114688, (const float*)d_in[15],
                                       wt + 131072, (const float*)d_in[17],
                                       sx, (float*)d_out, n);
}